// Round 2
// baseline (174.419 us; speedup 1.0000x reference)
//
#include <hip/hip_runtime.h>
#include <hip/hip_bf16.h>

#define B_  8
#define T_  1024
#define DI_ 256
#define C_  1024
#define O_  1024
#define KW  9
#define EPSF 1e-12f

typedef unsigned short u16;
typedef u16   ushort8 __attribute__((ext_vector_type(8)));
typedef u16   ushort4v __attribute__((ext_vector_type(4)));
typedef __bf16 bf16x8 __attribute__((ext_vector_type(8)));
typedef float  f32x4  __attribute__((ext_vector_type(4)));

__device__ __forceinline__ float bf2f(u16 u) {
    union { unsigned int i; float f; } z; z.i = ((unsigned int)u) << 16; return z.f;
}
__device__ __forceinline__ u16 f2bf(float f) {
    union { float f; unsigned int i; } z; z.f = f;
    unsigned int i = z.i;
    i += 0x7FFFu + ((i >> 16) & 1u);   // RNE
    return (u16)(i >> 16);
}
__device__ __forceinline__ float mishf(float v) {
    float u = __expf(v);
    float w = 1.f + u;
    return v * (1.f - 2.f / (w * w + 1.f));
}

// ---------------- f32 -> bf16 convert (vectorized, n multiple of 4) ---------
__global__ __launch_bounds__(256)
void cvt_k(const float* __restrict__ in, u16* __restrict__ out, int n4)
{
    int i = blockIdx.x * 256 + threadIdx.x;
    if (i >= n4) return;
    float4 v = ((const float4*)in)[i];
    ushort4v o;
    o.x = f2bf(v.x); o.y = f2bf(v.y); o.z = f2bf(v.z); o.w = f2bf(v.w);
    ((ushort4v*)out)[i] = o;
}

// ---------------- depthwise weight norm: dwf[b][c][k] = d_w/||.||_k * d_g ---
__global__ __launch_bounds__(256)
void dnorm_k(const float* __restrict__ d_w, const float* __restrict__ d_g,
             float* __restrict__ dwf)
{
    __shared__ float red[KW][256];
    __shared__ float nrm[KW];
    const int b = blockIdx.x;
    const int tid = threadIdx.x;
    float s[KW];
#pragma unroll
    for (int k = 0; k < KW; k++) s[k] = 0.f;
    for (int c = tid; c < C_; c += 256) {
#pragma unroll
        for (int k = 0; k < KW; k++) {
            float v = d_w[((size_t)b * C_ + c) * KW + k];
            s[k] += v * v;
        }
    }
#pragma unroll
    for (int k = 0; k < KW; k++) red[k][tid] = s[k];
    __syncthreads();
    if (tid < KW) {
        float t = 0.f;
        for (int i = 0; i < 256; i++) t += red[tid][i];
        nrm[tid] = fmaxf(sqrtf(t), EPSF);
    }
    __syncthreads();
    for (int c = tid; c < C_; c += 256) {
        float g = d_g[(size_t)b * C_ + c];
#pragma unroll
        for (int k = 0; k < KW; k++)
            dwf[((size_t)b * C_ + c) * KW + k] =
                d_w[((size_t)b * C_ + c) * KW + k] / nrm[k] * g;
    }
}

// ---------------- pointwise norm: inv_np[b][o] = 1/max(||p_w[:,o]||, eps) ----
__global__ __launch_bounds__(256)
void pnorm_k(const float* __restrict__ p_w, float* __restrict__ inv_np)
{
    const int b = blockIdx.y;
    const int o = blockIdx.x * 256 + threadIdx.x;
    const float* pw = p_w + (size_t)b * C_ * O_;
    float s = 0.f;
    for (int c = 0; c < C_; c++) {
        float v = pw[(size_t)c * O_ + o];
        s += v * v;
    }
    inv_np[b * O_ + o] = 1.f / fmaxf(sqrtf(s), EPSF);
}

// -------- transpose + scale: pwT[b][o][c] = p_w[b][c][o]*p_g[b][c]*inv_np[b][o]
__global__ __launch_bounds__(256)
void ptrans_k(const float* __restrict__ p_w, const float* __restrict__ p_g,
              const float* __restrict__ inv_np, u16* __restrict__ pwT)
{
    __shared__ float ts[64][65];
    const int b  = blockIdx.z;
    const int c0 = blockIdx.y * 64, o0 = blockIdx.x * 64;
    const int tid = threadIdx.x;
    const int col = tid & 63;
    for (int r = tid >> 6; r < 64; r += 4) {
        float g = p_g[(size_t)b * C_ + c0 + r];
        ts[r][col] = p_w[((size_t)b * C_ + c0 + r) * O_ + o0 + col] * g;
    }
    __syncthreads();
    for (int r = tid >> 6; r < 64; r += 4) {
        float inv = inv_np[b * O_ + o0 + r];
        pwT[((size_t)b * O_ + o0 + r) * C_ + c0 + col] = f2bf(ts[col][r] * inv);
    }
}

// ---------------- depthwise conv along t + transpose write -------------------
// y1gT[b][t][c] = sum_k h[b][c][t+k-4]*dwf[b][c][k] + d_b[b][c]
__global__ __launch_bounds__(256)
void dwconv_k(const u16* __restrict__ h, const float* __restrict__ dwf,
              const float* __restrict__ d_b, u16* __restrict__ y1gT)
{
    __shared__ u16 hs[64][74];
    const int b  = blockIdx.z;
    const int c0 = blockIdx.y * 64, t0 = blockIdx.x * 64;
    const int tid = threadIdx.x;
    const u16* hb = h + ((size_t)b * C_ + c0) * T_;
    for (int idx = tid; idx < 64 * 72; idx += 256) {
        int cc = idx / 72, tt = idx % 72;
        int t = t0 + tt - 4;
        u16 v = 0;
        if (t >= 0 && t < T_) v = hb[(size_t)cc * T_ + t];
        hs[cc][tt] = v;
    }
    __syncthreads();
    const int cc = tid & 63;
    const int c  = c0 + cc;
    float w[KW];
#pragma unroll
    for (int k = 0; k < KW; k++) w[k] = dwf[((size_t)b * C_ + c) * KW + k];
    const float bb = d_b[(size_t)b * C_ + c];
    for (int tt = tid >> 6; tt < 64; tt += 4) {
        float s = bb;
#pragma unroll
        for (int k = 0; k < KW; k++) s += bf2f(hs[cc][tt + k]) * w[k];
        y1gT[((size_t)b * T_ + t0 + tt) * C_ + c] = f2bf(s);
    }
}

// ---------------- shared GEMM: D[M,N] = A[M,K] * Bt[N,K]^T, K-contig both ----
// EPI 0: D(bf16) = mish(v + bias[row])          (bias = w1_b, row = channel)
// EPI 1: D(bf16) = v + bias[col]                (bias = p_b per batch)
// EPI 2: D(f32)  = v + bias[col] + X[row,col]   (bias = w2_b, X = residual x)
template<int EPI>
__global__ __launch_bounds__(256)
void gemm_nk(const u16* __restrict__ A, const u16* __restrict__ Bt,
             void* __restrict__ Dv, const float* __restrict__ bias,
             const float* __restrict__ resid,
             int M, int N, int Kd,
             long sA, long sB, long sD, long sBias)
{
    __shared__ u16 As[128][40];
    __shared__ u16 Bs[128][40];
    const int b = blockIdx.z;
    A  += (size_t)b * sA;
    Bt += (size_t)b * sB;
    const float* bi = bias + (size_t)b * sBias;
    const float* X  = (EPI == 2) ? resid + (size_t)b * sD : nullptr;
    u16*   Db = (EPI == 2) ? nullptr : (u16*)Dv + (size_t)b * sD;
    float* Df = (EPI == 2) ? (float*)Dv + (size_t)b * sD : nullptr;

    const int m0 = blockIdx.y * 128, n0 = blockIdx.x * 128;
    const int tid  = threadIdx.x;
    const int lane = tid & 63, wave = tid >> 6;
    const int wm = (wave & 1) * 64, wn = (wave >> 1) * 64;
    const int lr = lane & 15, kg = (lane >> 4) * 8;

    f32x4 acc[4][4];
#pragma unroll
    for (int i = 0; i < 4; i++)
#pragma unroll
        for (int j = 0; j < 4; j++) acc[i][j] = (f32x4){0.f, 0.f, 0.f, 0.f};

    const int ar = tid >> 2;        // 0..63
    const int ac = (tid & 3) * 8;   // 0,8,16,24

    for (int k0 = 0; k0 < Kd; k0 += 32) {
        __syncthreads();
        *(ushort8*)&As[ar][ac]      = *(const ushort8*)&A [(size_t)(m0 + ar)      * Kd + k0 + ac];
        *(ushort8*)&As[ar + 64][ac] = *(const ushort8*)&A [(size_t)(m0 + ar + 64) * Kd + k0 + ac];
        *(ushort8*)&Bs[ar][ac]      = *(const ushort8*)&Bt[(size_t)(n0 + ar)      * Kd + k0 + ac];
        *(ushort8*)&Bs[ar + 64][ac] = *(const ushort8*)&Bt[(size_t)(n0 + ar + 64) * Kd + k0 + ac];
        __syncthreads();
        bf16x8 av[4], bv[4];
#pragma unroll
        for (int i = 0; i < 4; i++) av[i] = *(const bf16x8*)&As[wm + i * 16 + lr][kg];
#pragma unroll
        for (int j = 0; j < 4; j++) bv[j] = *(const bf16x8*)&Bs[wn + j * 16 + lr][kg];
#pragma unroll
        for (int i = 0; i < 4; i++)
#pragma unroll
            for (int j = 0; j < 4; j++)
                acc[i][j] = __builtin_amdgcn_mfma_f32_16x16x32_bf16(av[i], bv[j], acc[i][j], 0, 0, 0);
    }

    const int r0 = (lane >> 4) * 4;
#pragma unroll
    for (int i = 0; i < 4; i++) {
#pragma unroll
        for (int j = 0; j < 4; j++) {
#pragma unroll
            for (int r = 0; r < 4; r++) {
                int row = m0 + wm + i * 16 + r0 + r;
                int col = n0 + wn + j * 16 + lr;
                float v = acc[i][j][r];
                if (EPI == 0) {
                    v += bi[row];
                    v = mishf(v);
                    Db[(size_t)row * N + col] = f2bf(v);
                } else if (EPI == 1) {
                    v += bi[col];
                    Db[(size_t)row * N + col] = f2bf(v);
                } else {
                    v += bi[col] + X[(size_t)row * N + col];
                    Df[(size_t)row * N + col] = v;
                }
            }
        }
    }
}

extern "C" void kernel_launch(void* const* d_in, const int* in_sizes, int n_in,
                              void* d_out, int out_size, void* d_ws, size_t ws_size,
                              hipStream_t stream)
{
    const float* x   = (const float*)d_in[0];
    const float* d_w = (const float*)d_in[1];
    const float* d_g = (const float*)d_in[2];
    const float* d_b = (const float*)d_in[3];
    const float* p_w = (const float*)d_in[4];
    const float* p_g = (const float*)d_in[5];
    const float* p_b = (const float*)d_in[6];
    const float* w1w = (const float*)d_in[7];
    const float* w1b = (const float*)d_in[8];
    const float* w2w = (const float*)d_in[9];
    const float* w2b = (const float*)d_in[10];
    float* out = (float*)d_out;

    char* ws = (char*)d_ws;
    const size_t SZ = (size_t)16777216;           // 8*1024*1024*2 bytes
    u16*   h    = (u16*)(ws);                     // [B][C][T] bf16
    u16*   y1gT = (u16*)(ws + SZ);                // [B][T][C] bf16
    u16*   pwT  = (u16*)(ws + 2 * SZ);            // [B][O][C] bf16
    u16*   y2T  = (u16*)(ws + 3 * SZ);            // [B][T][O] bf16
    u16*   xb   = (u16*)(ws + 4 * SZ);            // [B][T][DI] bf16 (4 MB)
    u16*   w1b16= (u16*)(ws + 4 * SZ + 4194304);  // [C][DI] bf16 (512 KB)
    u16*   w2b16= (u16*)(ws + 4 * SZ + 4718592);  // [DI][O] bf16 (512 KB)
    float* dwf  = (float*)(ws + 4 * SZ + 5242880);          // B*C*KW f32
    float* inv  = (float*)(ws + 4 * SZ + 5242880 + 294912); // B*O f32

    cvt_k<<<dim3((B_ * T_ * DI_) / 4 / 256), 256, 0, stream>>>(x,   xb,    (B_ * T_ * DI_) / 4);
    cvt_k<<<dim3((C_ * DI_) / 4 / 256),      256, 0, stream>>>(w1w, w1b16, (C_ * DI_) / 4);
    cvt_k<<<dim3((DI_ * O_) / 4 / 256),      256, 0, stream>>>(w2w, w2b16, (DI_ * O_) / 4);

    dnorm_k<<<dim3(B_), 256, 0, stream>>>(d_w, d_g, dwf);
    pnorm_k<<<dim3(O_ / 256, B_), 256, 0, stream>>>(p_w, inv);
    ptrans_k<<<dim3(O_ / 64, C_ / 64, B_), 256, 0, stream>>>(p_w, p_g, inv, pwT);

    // GEMM1: h[c][t] = mish(w1w[c,:] . x[t,:] + w1b[c]);  M=C, N=T, K=DI
    gemm_nk<0><<<dim3(T_ / 128, C_ / 128, B_), 256, 0, stream>>>(
        w1b16, xb, h, w1b, nullptr, C_, T_, DI_,
        0L, (long)T_ * DI_, (long)C_ * T_, 0L);

    dwconv_k<<<dim3(T_ / 64, C_ / 64, B_), 256, 0, stream>>>(h, dwf, d_b, y1gT);

    // GEMM2: y2T[t][o] = y1gT[t,:] . pwT[o,:] + p_b[o];  M=T, N=O, K=C
    gemm_nk<1><<<dim3(O_ / 128, T_ / 128, B_), 256, 0, stream>>>(
        y1gT, pwT, y2T, p_b, nullptr, T_, O_, C_,
        (long)T_ * C_, (long)O_ * C_, (long)T_ * O_, (long)O_);

    // GEMM3: out[t][i] = y2T[t,:] . w2w[i,:] + w2b[i] + x[t][i];  M=T, N=DI, K=O
    gemm_nk<2><<<dim3(DI_ / 128, T_ / 128, B_), 256, 0, stream>>>(
        y2T, w2b16, out, w2b, x, T_, DI_, O_,
        (long)T_ * O_, 0L, (long)T_ * DI_, 0L);
}

// Round 3
// 136.460 us; speedup vs baseline: 1.2782x; 1.2782x over previous
//
#include <hip/hip_runtime.h>
#include <hip/hip_bf16.h>

#define B_  8
#define T_  1024
#define DI_ 256
#define C_  1024
#define O_  1024
#define KW  9
#define EPSF 1e-12f

typedef unsigned short u16;
typedef u16   ushort8 __attribute__((ext_vector_type(8)));
typedef u16   ushort4v __attribute__((ext_vector_type(4)));
typedef __bf16 bf16x8 __attribute__((ext_vector_type(8)));
typedef float  f32x4  __attribute__((ext_vector_type(4)));

#define GLOAD_LDS16(g, l) __builtin_amdgcn_global_load_lds( \
    (const __attribute__((address_space(1))) void*)(g),      \
    (__attribute__((address_space(3))) void*)(l), 16, 0, 0)

__device__ __forceinline__ float bf2f(u16 u) {
    union { unsigned int i; float f; } z; z.i = ((unsigned int)u) << 16; return z.f;
}
__device__ __forceinline__ u16 f2bf(float f) {
    union { float f; unsigned int i; } z; z.f = f;
    unsigned int i = z.i;
    i += 0x7FFFu + ((i >> 16) & 1u);   // RNE
    return (u16)(i >> 16);
}
__device__ __forceinline__ float mishf(float v) {
    float u = __expf(v);
    float w = 1.f + u;
    return v * (1.f - 2.f / (w * w + 1.f));
}

// ---------------- f32 -> bf16 convert (vectorized, n multiple of 4) ---------
__global__ __launch_bounds__(256)
void cvt_k(const float* __restrict__ in, u16* __restrict__ out, int n4)
{
    int i = blockIdx.x * 256 + threadIdx.x;
    if (i >= n4) return;
    float4 v = ((const float4*)in)[i];
    ushort4v o;
    o.x = f2bf(v.x); o.y = f2bf(v.y); o.z = f2bf(v.z); o.w = f2bf(v.w);
    ((ushort4v*)out)[i] = o;
}

// ---------------- depthwise weight norm: dwf[b][c][k] = d_w/||.||_k * d_g ---
__global__ __launch_bounds__(256)
void dnorm_k(const float* __restrict__ d_w, const float* __restrict__ d_g,
             float* __restrict__ dwf)
{
    __shared__ float red[KW][256];
    __shared__ float nrm[KW];
    const int b = blockIdx.x;
    const int tid = threadIdx.x;
    float s[KW];
#pragma unroll
    for (int k = 0; k < KW; k++) s[k] = 0.f;
    for (int c = tid; c < C_; c += 256) {
#pragma unroll
        for (int k = 0; k < KW; k++) {
            float v = d_w[((size_t)b * C_ + c) * KW + k];
            s[k] += v * v;
        }
    }
#pragma unroll
    for (int k = 0; k < KW; k++) red[k][tid] = s[k];
    __syncthreads();
    if (tid < KW) {
        float t = 0.f;
        for (int i = 0; i < 256; i++) t += red[tid][i];
        nrm[tid] = fmaxf(sqrtf(t), EPSF);
    }
    __syncthreads();
    for (int c = tid; c < C_; c += 256) {
        float g = d_g[(size_t)b * C_ + c];
#pragma unroll
        for (int k = 0; k < KW; k++)
            dwf[((size_t)b * C_ + c) * KW + k] =
                d_w[((size_t)b * C_ + c) * KW + k] / nrm[k] * g;
    }
}

// ------- pointwise norm pass 1: partial[b][ch][o] = sum_{c in chunk} pw^2 ---
__global__ __launch_bounds__(256)
void pnorm1_k(const float* __restrict__ p_w, float* __restrict__ partial)
{
    const int b  = blockIdx.z;
    const int ch = blockIdx.y;              // 32 chunks of 32 channels
    const int o  = blockIdx.x * 256 + threadIdx.x;
    const float* pw = p_w + ((size_t)b * C_ + ch * 32) * O_;
    float s = 0.f;
#pragma unroll 8
    for (int c = 0; c < 32; c++) {
        float v = pw[(size_t)c * O_ + o];
        s += v * v;
    }
    partial[((size_t)b * 32 + ch) * O_ + o] = s;
}

// ------- pointwise norm pass 2: inv_np[b][o] = 1/max(sqrt(sum),eps) ---------
__global__ __launch_bounds__(256)
void pfin_k(const float* __restrict__ partial, float* __restrict__ inv_np)
{
    const int b = blockIdx.y;
    const int o = blockIdx.x * 256 + threadIdx.x;
    float s = 0.f;
#pragma unroll
    for (int ch = 0; ch < 32; ch++)
        s += partial[((size_t)b * 32 + ch) * O_ + o];
    inv_np[b * O_ + o] = 1.f / fmaxf(sqrtf(s), EPSF);
}

// -------- transpose + scale: pwT[b][o][c] = p_w[b][c][o]*p_g[b][c]*inv_np[b][o]
__global__ __launch_bounds__(256)
void ptrans_k(const float* __restrict__ p_w, const float* __restrict__ p_g,
              const float* __restrict__ inv_np, u16* __restrict__ pwT)
{
    __shared__ float ts[64][65];
    const int b  = blockIdx.z;
    const int c0 = blockIdx.y * 64, o0 = blockIdx.x * 64;
    const int tid = threadIdx.x;
    const int col = tid & 63;
    for (int r = tid >> 6; r < 64; r += 4) {
        float g = p_g[(size_t)b * C_ + c0 + r];
        ts[r][col] = p_w[((size_t)b * C_ + c0 + r) * O_ + o0 + col] * g;
    }
    __syncthreads();
    for (int r = tid >> 6; r < 64; r += 4) {
        float inv = inv_np[b * O_ + o0 + r];
        pwT[((size_t)b * O_ + o0 + r) * C_ + c0 + col] = f2bf(ts[col][r] * inv);
    }
}

// ---------------- depthwise conv along t + transpose write -------------------
// y1gT[b][t][c] = sum_k h[b][c][t+k-4]*dwf[b][c][k] + d_b[b][c]
__global__ __launch_bounds__(256)
void dwconv_k(const u16* __restrict__ h, const float* __restrict__ dwf,
              const float* __restrict__ d_b, u16* __restrict__ y1gT)
{
    __shared__ u16 hs[64][74];
    const int b  = blockIdx.z;
    const int c0 = blockIdx.y * 64, t0 = blockIdx.x * 64;
    const int tid = threadIdx.x;
    const u16* hb = h + ((size_t)b * C_ + c0) * T_;
    for (int idx = tid; idx < 64 * 72; idx += 256) {
        int cc = idx / 72, tt = idx % 72;
        int t = t0 + tt - 4;
        u16 v = 0;
        if (t >= 0 && t < T_) v = hb[(size_t)cc * T_ + t];
        hs[cc][tt] = v;
    }
    __syncthreads();
    const int cc = tid & 63;
    const int c  = c0 + cc;
    float w[KW];
#pragma unroll
    for (int k = 0; k < KW; k++) w[k] = dwf[((size_t)b * C_ + c) * KW + k];
    const float bb = d_b[(size_t)b * C_ + c];
    for (int tt = tid >> 6; tt < 64; tt += 4) {
        float s = bb;
#pragma unroll
        for (int k = 0; k < KW; k++) s += bf2f(hs[cc][tt + k]) * w[k];
        y1gT[((size_t)b * T_ + t0 + tt) * C_ + c] = f2bf(s);
    }
}

// ---------------- shared GEMM: D[M,N] = A[M,K] * Bt[N,K]^T, K-contig both ----
// m97 structure: unpadded LDS + global_load_lds width-16, 2-barrier K-loop.
// EPI 0: D(bf16) = mish(v + bias[row])          (bias = w1_b, row = channel)
// EPI 1: D(bf16) = v + bias[col]                (bias = p_b per batch)
// EPI 2: D(f32)  = v + bias[col] + X[row,col]   (bias = w2_b, X = residual x)
template<int EPI>
__global__ __launch_bounds__(256)
void gemm_nk(const u16* __restrict__ A, const u16* __restrict__ Bt,
             void* __restrict__ Dv, const float* __restrict__ bias,
             const float* __restrict__ resid,
             int M, int N, int Kd,
             long sA, long sB, long sD, long sBias)
{
    __shared__ u16 As[128 * 32];
    __shared__ u16 Bs[128 * 32];
    const int b = blockIdx.z;
    A  += (size_t)b * sA;
    Bt += (size_t)b * sB;
    const float* bi = bias + (size_t)b * sBias;
    const float* X  = (EPI == 2) ? resid + (size_t)b * sD : nullptr;
    u16*   Db = (EPI == 2) ? nullptr : (u16*)Dv + (size_t)b * sD;
    float* Df = (EPI == 2) ? (float*)Dv + (size_t)b * sD : nullptr;

    const int m0 = blockIdx.y * 128, n0 = blockIdx.x * 128;
    const int tid  = threadIdx.x;
    const int lane = tid & 63, wave = tid >> 6;
    const int wm = (wave & 1) * 64, wn = (wave >> 1) * 64;
    const int lr = lane & 15, kg = (lane >> 4) * 8;

    // staging: each wave owns 16 rows (1024 B) per chunk; lane l covers
    // row wave*16 + l/4, col (l&3)*8 elems -> LDS base + l*16 bytes (linear)
    const int srow = wave * 16 + (lane >> 2);
    const int scol = (lane & 3) * 8;
    u16* ldsA0 = &As[wave * 512];
    u16* ldsA1 = &As[2048 + wave * 512];
    u16* ldsB0 = &Bs[wave * 512];
    u16* ldsB1 = &Bs[2048 + wave * 512];

    f32x4 acc[4][4];
#pragma unroll
    for (int i = 0; i < 4; i++)
#pragma unroll
        for (int j = 0; j < 4; j++) acc[i][j] = (f32x4){0.f, 0.f, 0.f, 0.f};

    for (int k0 = 0; k0 < Kd; k0 += 32) {
        __syncthreads();
        GLOAD_LDS16(&A [(size_t)(m0 + srow)      * Kd + k0 + scol], ldsA0);
        GLOAD_LDS16(&A [(size_t)(m0 + 64 + srow) * Kd + k0 + scol], ldsA1);
        GLOAD_LDS16(&Bt[(size_t)(n0 + srow)      * Kd + k0 + scol], ldsB0);
        GLOAD_LDS16(&Bt[(size_t)(n0 + 64 + srow) * Kd + k0 + scol], ldsB1);
        __syncthreads();
        bf16x8 av[4], bv[4];
#pragma unroll
        for (int i = 0; i < 4; i++) av[i] = *(const bf16x8*)&As[(wm + i * 16 + lr) * 32 + kg];
#pragma unroll
        for (int j = 0; j < 4; j++) bv[j] = *(const bf16x8*)&Bs[(wn + j * 16 + lr) * 32 + kg];
#pragma unroll
        for (int i = 0; i < 4; i++)
#pragma unroll
            for (int j = 0; j < 4; j++)
                acc[i][j] = __builtin_amdgcn_mfma_f32_16x16x32_bf16(av[i], bv[j], acc[i][j], 0, 0, 0);
    }

    const int r0 = (lane >> 4) * 4;
#pragma unroll
    for (int i = 0; i < 4; i++) {
#pragma unroll
        for (int j = 0; j < 4; j++) {
#pragma unroll
            for (int r = 0; r < 4; r++) {
                int row = m0 + wm + i * 16 + r0 + r;
                int col = n0 + wn + j * 16 + lr;
                float v = acc[i][j][r];
                if (EPI == 0) {
                    v += bi[row];
                    v = mishf(v);
                    Db[(size_t)row * N + col] = f2bf(v);
                } else if (EPI == 1) {
                    v += bi[col];
                    Db[(size_t)row * N + col] = f2bf(v);
                } else {
                    v += bi[col] + X[(size_t)row * N + col];
                    Df[(size_t)row * N + col] = v;
                }
            }
        }
    }
}

extern "C" void kernel_launch(void* const* d_in, const int* in_sizes, int n_in,
                              void* d_out, int out_size, void* d_ws, size_t ws_size,
                              hipStream_t stream)
{
    const float* x   = (const float*)d_in[0];
    const float* d_w = (const float*)d_in[1];
    const float* d_g = (const float*)d_in[2];
    const float* d_b = (const float*)d_in[3];
    const float* p_w = (const float*)d_in[4];
    const float* p_g = (const float*)d_in[5];
    const float* p_b = (const float*)d_in[6];
    const float* w1w = (const float*)d_in[7];
    const float* w1b = (const float*)d_in[8];
    const float* w2w = (const float*)d_in[9];
    const float* w2b = (const float*)d_in[10];
    float* out = (float*)d_out;

    char* ws = (char*)d_ws;
    const size_t SZ = (size_t)16777216;           // 8*1024*1024*2 bytes
    u16*   h    = (u16*)(ws);                     // [B][C][T] bf16
    u16*   y1gT = (u16*)(ws + SZ);                // [B][T][C] bf16
    u16*   pwT  = (u16*)(ws + 2 * SZ);            // [B][O][C] bf16
    u16*   y2T  = (u16*)(ws + 3 * SZ);            // [B][T][O] bf16
    u16*   xb   = (u16*)(ws + 4 * SZ);            // [B][T][DI] bf16 (4 MB)
    u16*   w1b16= (u16*)(ws + 4 * SZ + 4194304);  // [C][DI] bf16 (512 KB)
    u16*   w2b16= (u16*)(ws + 4 * SZ + 4718592);  // [DI][O] bf16 (512 KB)
    float* dwf  = (float*)(ws + 4 * SZ + 5242880);           // B*C*KW f32
    float* inv  = (float*)(ws + 4 * SZ + 5242880 + 294912);  // B*O f32
    float* part = (float*)(ws + 4 * SZ + 5242880 + 327680);  // B*32*O f32 (1 MB)

    cvt_k<<<dim3((B_ * T_ * DI_) / 4 / 256), 256, 0, stream>>>(x,   xb,    (B_ * T_ * DI_) / 4);
    cvt_k<<<dim3((C_ * DI_) / 4 / 256),      256, 0, stream>>>(w1w, w1b16, (C_ * DI_) / 4);
    cvt_k<<<dim3((DI_ * O_) / 4 / 256),      256, 0, stream>>>(w2w, w2b16, (DI_ * O_) / 4);

    dnorm_k<<<dim3(B_), 256, 0, stream>>>(d_w, d_g, dwf);
    pnorm1_k<<<dim3(O_ / 256, 32, B_), 256, 0, stream>>>(p_w, part);
    pfin_k<<<dim3(O_ / 256, B_), 256, 0, stream>>>(part, inv);
    ptrans_k<<<dim3(O_ / 64, C_ / 64, B_), 256, 0, stream>>>(p_w, p_g, inv, pwT);

    // GEMM1: h[c][t] = mish(w1w[c,:] . x[t,:] + w1b[c]);  M=C, N=T, K=DI
    gemm_nk<0><<<dim3(T_ / 128, C_ / 128, B_), 256, 0, stream>>>(
        w1b16, xb, h, w1b, nullptr, C_, T_, DI_,
        0L, (long)T_ * DI_, (long)C_ * T_, 0L);

    dwconv_k<<<dim3(T_ / 64, C_ / 64, B_), 256, 0, stream>>>(h, dwf, d_b, y1gT);

    // GEMM2: y2T[t][o] = y1gT[t,:] . pwT[o,:] + p_b[o];  M=T, N=O, K=C
    gemm_nk<1><<<dim3(O_ / 128, T_ / 128, B_), 256, 0, stream>>>(
        y1gT, pwT, y2T, p_b, nullptr, T_, O_, C_,
        (long)T_ * C_, (long)O_ * C_, (long)T_ * O_, (long)O_);

    // GEMM3: out[t][i] = y2T[t,:] . w2w[i,:] + w2b[i] + x[t][i];  M=T, N=DI, K=O
    gemm_nk<2><<<dim3(DI_ / 128, T_ / 128, B_), 256, 0, stream>>>(
        y2T, w2b16, out, w2b, x, T_, DI_, O_,
        (long)T_ * O_, 0L, (long)T_ * DI_, 0L);
}

// Round 4
// 116.414 us; speedup vs baseline: 1.4983x; 1.1722x over previous
//
#include <hip/hip_runtime.h>
#include <hip/hip_bf16.h>

#define B_  8
#define T_  1024
#define DI_ 256
#define C_  1024
#define O_  1024
#define KW  9
#define BT_ 8192
#define EPSF 1e-12f

typedef unsigned short u16;
typedef u16   ushort8 __attribute__((ext_vector_type(8)));
typedef u16   ushort4v __attribute__((ext_vector_type(4)));
typedef __bf16 bf16x8 __attribute__((ext_vector_type(8)));
typedef float  f32x4  __attribute__((ext_vector_type(4)));

#define GLOAD_LDS16(g, l) __builtin_amdgcn_global_load_lds( \
    (const __attribute__((address_space(1))) void*)(g),      \
    (__attribute__((address_space(3))) void*)(l), 16, 0, 0)

__device__ __forceinline__ float bf2f(u16 u) {
    union { unsigned int i; float f; } z; z.i = ((unsigned int)u) << 16; return z.f;
}
__device__ __forceinline__ u16 f2bf(float f) {
    union { float f; unsigned int i; } z; z.f = f;
    unsigned int i = z.i;
    i += 0x7FFFu + ((i >> 16) & 1u);   // RNE
    return (u16)(i >> 16);
}
__device__ __forceinline__ float mishf(float v) {
    float u = __expf(v);
    float w = 1.f + u;
    return v * (1.f - 2.f / (w * w + 1.f));
}

// ---------------- f32 -> bf16 convert (vectorized, n multiple of 4) ---------
__global__ __launch_bounds__(256)
void cvt_k(const float* __restrict__ in, u16* __restrict__ out, int n4)
{
    int i = blockIdx.x * 256 + threadIdx.x;
    if (i >= n4) return;
    float4 v = ((const float4*)in)[i];
    ushort4v o;
    o.x = f2bf(v.x); o.y = f2bf(v.y); o.z = f2bf(v.z); o.w = f2bf(v.w);
    ((ushort4v*)out)[i] = o;
}

// ---------------- depthwise weight norm: dwf[b][c][k] = d_w/||.||_k * d_g ---
__global__ __launch_bounds__(256)
void dnorm_k(const float* __restrict__ d_w, const float* __restrict__ d_g,
             float* __restrict__ dwf)
{
    __shared__ float red[KW][256];
    __shared__ float nrm[KW];
    const int b = blockIdx.x;
    const int tid = threadIdx.x;
    float s[KW];
#pragma unroll
    for (int k = 0; k < KW; k++) s[k] = 0.f;
    for (int c = tid; c < C_; c += 256) {
#pragma unroll
        for (int k = 0; k < KW; k++) {
            float v = d_w[((size_t)b * C_ + c) * KW + k];
            s[k] += v * v;
        }
    }
#pragma unroll
    for (int k = 0; k < KW; k++) red[k][tid] = s[k];
    __syncthreads();
    if (tid < KW) {
        float t = 0.f;
        for (int i = 0; i < 256; i++) t += red[tid][i];
        nrm[tid] = fmaxf(sqrtf(t), EPSF);
    }
    __syncthreads();
    for (int c = tid; c < C_; c += 256) {
        float g = d_g[(size_t)b * C_ + c];
#pragma unroll
        for (int k = 0; k < KW; k++)
            dwf[((size_t)b * C_ + c) * KW + k] =
                d_w[((size_t)b * C_ + c) * KW + k] / nrm[k] * g;
    }
}

// -------- transpose + gain + fused sum-of-squares partials -------------------
// pwT[b][o][c] = p_w[b][c][o] * p_g[b][c]   (inv_np applied in GEMM2 epilogue)
// part[b][cchunk][o] = sum_{c in chunk} p_w^2
__global__ __launch_bounds__(256)
void ptrans_k(const float* __restrict__ p_w, const float* __restrict__ p_g,
              float* __restrict__ part, u16* __restrict__ pwT)
{
    __shared__ float ts[64][65];
    __shared__ float sq[4][64];
    const int b  = blockIdx.z;
    const int c0 = blockIdx.y * 64, o0 = blockIdx.x * 64;
    const int tid = threadIdx.x;
    const int col = tid & 63;
    const int rg  = tid >> 6;
    float ssq = 0.f;
    for (int r = rg; r < 64; r += 4) {
        float v = p_w[((size_t)b * C_ + c0 + r) * O_ + o0 + col];
        ssq += v * v;
        ts[r][col] = v * p_g[(size_t)b * C_ + c0 + r];
    }
    sq[rg][col] = ssq;
    __syncthreads();
    if (tid < 64)
        part[((size_t)b * 16 + blockIdx.y) * O_ + o0 + tid] =
            sq[0][tid] + sq[1][tid] + sq[2][tid] + sq[3][tid];
    for (int r = rg; r < 64; r += 4)
        pwT[((size_t)b * O_ + o0 + r) * C_ + c0 + col] = f2bf(ts[col][r]);
}

// ------- finalize: inv_np[b][o] = 1/max(sqrt(sum_ch part),eps) ---------------
__global__ __launch_bounds__(256)
void pfin_k(const float* __restrict__ part, float* __restrict__ inv_np)
{
    const int b = blockIdx.y;
    const int o = blockIdx.x * 256 + threadIdx.x;
    float s = 0.f;
#pragma unroll
    for (int ch = 0; ch < 16; ch++)
        s += part[((size_t)b * 16 + ch) * O_ + o];
    inv_np[b * O_ + o] = 1.f / fmaxf(sqrtf(s), EPSF);
}

// ---------------- depthwise conv along t + transpose write -------------------
// h layout [C][B*T]; y1gT[bt][c] = sum_k h[c][bt+k-4]*dwf[b][c][k] + d_b[b][c]
__global__ __launch_bounds__(256)
void dwconv_k(const u16* __restrict__ h, const float* __restrict__ dwf,
              const float* __restrict__ d_b, u16* __restrict__ y1gT)
{
    __shared__ u16 hs[64][74];
    const int b  = blockIdx.z;
    const int c0 = blockIdx.y * 64, t0 = blockIdx.x * 64;
    const int tid = threadIdx.x;
    for (int idx = tid; idx < 64 * 72; idx += 256) {
        int cc = idx / 72, tt = idx % 72;
        int t = t0 + tt - 4;
        u16 v = 0;
        if (t >= 0 && t < T_) v = h[(size_t)(c0 + cc) * BT_ + b * T_ + t];
        hs[cc][tt] = v;
    }
    __syncthreads();
    const int cc = tid & 63;
    const int c  = c0 + cc;
    float w[KW];
#pragma unroll
    for (int k = 0; k < KW; k++) w[k] = dwf[((size_t)b * C_ + c) * KW + k];
    const float bb = d_b[(size_t)b * C_ + c];
    for (int tt = tid >> 6; tt < 64; tt += 4) {
        float s = bb;
#pragma unroll
        for (int k = 0; k < KW; k++) s += bf2f(hs[cc][tt + k]) * w[k];
        y1gT[((size_t)b * T_ + t0 + tt) * C_ + c] = f2bf(s);
    }
}

// ---------------- shared GEMM: D[M,N] = A[M,K] * Bt[N,K]^T, K-contig both ----
// BK=64, XOR-swizzled LDS (slot ^= row&7), global_load_lds width-16.
// TNF = n-frags per wave (4 -> 128-wide tile, 2 -> 64-wide tile).
// EPI 0: D(bf16) = mish(v + bias[row])            (GEMM1: bias=w1_b)
// EPI 1: D(bf16) = v*inv[col] + bias[col]         (GEMM2: per-batch pwT/p_b)
// EPI 2: D(f32)  = v + bias[col] + X[row,col]     (GEMM3: bias=w2_b, X=resid)
template<int EPI, int TNF>
__global__ __launch_bounds__(256)
void gemm_nk(const u16* __restrict__ A, const u16* __restrict__ Bt,
             void* __restrict__ Dv, const float* __restrict__ bias,
             const float* __restrict__ extra,
             int M, int N, int Kd)
{
    __shared__ u16 As[128 * 64];
    __shared__ u16 Bs[TNF * 32 * 64];

    const int m0 = blockIdx.y * 128, n0 = blockIdx.x * (TNF * 32);
    // batch index for per-batch operands (GEMM2): M rows are b*T_+t
    const int b = (EPI == 1) ? (m0 >> 10) : 0;
    if (EPI == 1) {
        Bt   += (size_t)b * O_ * C_;
        bias += (size_t)b * O_;
        extra+= (size_t)b * O_;   // inv_np
    }
    u16*   Db = (EPI == 2) ? nullptr : (u16*)Dv;
    float* Df = (EPI == 2) ? (float*)Dv : nullptr;
    const float* X = (EPI == 2) ? extra : nullptr;

    const int tid  = threadIdx.x;
    const int lane = tid & 63, wave = tid >> 6;
    const int wm = (wave & 1) * 64, wn = (wave >> 1) * (TNF * 16);
    const int lr = lane & 15;

    // staging: instr covers 8 rows x 128B; source col pre-swizzled (lane-const)
    const int sbase = wave * 8;
    const int srowL = lane >> 3;
    const int scolE = ((lane & 7) ^ srowL) * 8;

    f32x4 acc[4][TNF];
#pragma unroll
    for (int i = 0; i < 4; i++)
#pragma unroll
        for (int j = 0; j < TNF; j++) acc[i][j] = (f32x4){0.f, 0.f, 0.f, 0.f};

    for (int k0 = 0; k0 < Kd; k0 += 64) {
        __syncthreads();
#pragma unroll
        for (int i = 0; i < 4; i++)
            GLOAD_LDS16(&A[(size_t)(m0 + i * 32 + sbase + srowL) * Kd + k0 + scolE],
                        &As[(i * 32 + sbase) * 64]);
#pragma unroll
        for (int i = 0; i < TNF; i++)
            GLOAD_LDS16(&Bt[(size_t)(n0 + i * 32 + sbase + srowL) * Kd + k0 + scolE],
                        &Bs[(i * 32 + sbase) * 64]);
        __syncthreads();

        bf16x8 av[2][4], bv[2][TNF];
#pragma unroll
        for (int kk = 0; kk < 2; kk++) {
            const int slot = (lane >> 4) + kk * 4;
            const int sw = (slot ^ (lr & 7)) << 3;
#pragma unroll
            for (int i = 0; i < 4; i++)
                av[kk][i] = *(const bf16x8*)&As[(wm + i * 16 + lr) * 64 + sw];
#pragma unroll
            for (int j = 0; j < TNF; j++)
                bv[kk][j] = *(const bf16x8*)&Bs[(wn + j * 16 + lr) * 64 + sw];
        }
#pragma unroll
        for (int kk = 0; kk < 2; kk++)
#pragma unroll
            for (int i = 0; i < 4; i++)
#pragma unroll
                for (int j = 0; j < TNF; j++)
                    acc[i][j] = __builtin_amdgcn_mfma_f32_16x16x32_bf16(
                        av[kk][i], bv[kk][j], acc[i][j], 0, 0, 0);
    }

    const int r0 = (lane >> 4) * 4;
#pragma unroll
    for (int i = 0; i < 4; i++) {
#pragma unroll
        for (int j = 0; j < TNF; j++) {
            const int col = n0 + wn + j * 16 + lr;
            float iv = (EPI == 1) ? extra[col] : 0.f;
#pragma unroll
            for (int r = 0; r < 4; r++) {
                const int row = m0 + wm + i * 16 + r0 + r;
                float v = acc[i][j][r];
                if (EPI == 0) {
                    v += bias[row];
                    v = mishf(v);
                    Db[(size_t)row * N + col] = f2bf(v);
                } else if (EPI == 1) {
                    v = v * iv + bias[col];
                    Db[(size_t)row * N + col] = f2bf(v);
                } else {
                    v += bias[col] + X[(size_t)row * N + col];
                    Df[(size_t)row * N + col] = v;
                }
            }
        }
    }
}

extern "C" void kernel_launch(void* const* d_in, const int* in_sizes, int n_in,
                              void* d_out, int out_size, void* d_ws, size_t ws_size,
                              hipStream_t stream)
{
    const float* x   = (const float*)d_in[0];
    const float* d_w = (const float*)d_in[1];
    const float* d_g = (const float*)d_in[2];
    const float* d_b = (const float*)d_in[3];
    const float* p_w = (const float*)d_in[4];
    const float* p_g = (const float*)d_in[5];
    const float* p_b = (const float*)d_in[6];
    const float* w1w = (const float*)d_in[7];
    const float* w1b = (const float*)d_in[8];
    const float* w2w = (const float*)d_in[9];
    const float* w2b = (const float*)d_in[10];
    float* out = (float*)d_out;

    char* ws = (char*)d_ws;
    const size_t SZ = (size_t)16777216;           // 16 MB
    u16*   h    = (u16*)(ws);                     // [C][B*T] bf16
    u16*   y1gT = (u16*)(ws + SZ);                // [B*T][C] bf16
    u16*   pwT  = (u16*)(ws + 2 * SZ);            // [B][O][C] bf16
    u16*   y2T  = (u16*)(ws + 3 * SZ);            // [B*T][O] bf16
    u16*   xb   = (u16*)(ws + 4 * SZ);            // [B*T][DI] bf16 (4 MB)
    u16*   w1b16= (u16*)(ws + 4 * SZ + 4194304);  // [C][DI] bf16
    u16*   w2b16= (u16*)(ws + 4 * SZ + 4718592);  // [DI][O] bf16
    float* dwf  = (float*)(ws + 4 * SZ + 5242880);           // B*C*KW f32
    float* inv  = (float*)(ws + 4 * SZ + 5242880 + 294912);  // B*O f32
    float* part = (float*)(ws + 4 * SZ + 5242880 + 327680);  // B*16*O f32

    cvt_k<<<dim3((BT_ * DI_) / 4 / 256), 256, 0, stream>>>(x,   xb,    (BT_ * DI_) / 4);
    cvt_k<<<dim3((C_ * DI_) / 4 / 256), 256, 0, stream>>>(w1w, w1b16, (C_ * DI_) / 4);
    cvt_k<<<dim3((DI_ * O_) / 4 / 256), 256, 0, stream>>>(w2w, w2b16, (DI_ * O_) / 4);

    dnorm_k<<<dim3(B_), 256, 0, stream>>>(d_w, d_g, dwf);
    ptrans_k<<<dim3(O_ / 64, C_ / 64, B_), 256, 0, stream>>>(p_w, p_g, part, pwT);
    pfin_k<<<dim3(O_ / 256, B_), 256, 0, stream>>>(part, inv);

    // GEMM1: h[c][bt] = mish(w1[c,:] . xb[bt,:] + w1b[c]);  M=C, N=B*T, K=DI
    gemm_nk<0, 4><<<dim3(BT_ / 128, C_ / 128), 256, 0, stream>>>(
        w1b16, xb, h, w1b, nullptr, C_, BT_, DI_);

    dwconv_k<<<dim3(T_ / 64, C_ / 64, B_), 256, 0, stream>>>(h, dwf, d_b, y1gT);

    // GEMM2: y2T[bt][o] = (y1gT[bt,:] . pwT[b][o,:])*inv[b][o] + p_b[b][o]
    gemm_nk<1, 4><<<dim3(O_ / 128, BT_ / 128), 256, 0, stream>>>(
        y1gT, pwT, y2T, p_b, inv, BT_, O_, C_);

    // GEMM3: out[bt][i] = y2T[bt,:] . w2[i,:] + w2b[i] + x[bt][i];  N=DI, 64-wide
    gemm_nk<2, 2><<<dim3(DI_ / 64, BT_ / 128), 256, 0, stream>>>(
        y2T, w2b16, out, w2b, x, BT_, DI_, O_);
}

// Round 5
// 110.224 us; speedup vs baseline: 1.5824x; 1.0562x over previous
//
#include <hip/hip_runtime.h>
#include <hip/hip_bf16.h>

#define B_  8
#define T_  1024
#define DI_ 256
#define C_  1024
#define O_  1024
#define KW  9
#define BT_ 8192
#define EPSF 1e-12f

typedef unsigned short u16;
typedef u16   ushort8 __attribute__((ext_vector_type(8)));
typedef u16   ushort4v __attribute__((ext_vector_type(4)));
typedef __bf16 bf16x8 __attribute__((ext_vector_type(8)));
typedef float  f32x4  __attribute__((ext_vector_type(4)));

#define GLOAD_LDS16(g, l) __builtin_amdgcn_global_load_lds( \
    (const __attribute__((address_space(1))) void*)(g),      \
    (__attribute__((address_space(3))) void*)(l), 16, 0, 0)

__device__ __forceinline__ float bf2f(u16 u) {
    union { unsigned int i; float f; } z; z.i = ((unsigned int)u) << 16; return z.f;
}
__device__ __forceinline__ u16 f2bf(float f) {
    union { float f; unsigned int i; } z; z.f = f;
    unsigned int i = z.i;
    i += 0x7FFFu + ((i >> 16) & 1u);   // RNE
    return (u16)(i >> 16);
}
__device__ __forceinline__ float mishf(float v) {
    float u = __expf(v);
    float w = 1.f + u;
    return v * (1.f - 2.f / (w * w + 1.f));
}

// ---------------- f32 -> bf16 convert (vectorized, n multiple of 4) ---------
__global__ __launch_bounds__(256)
void cvt_k(const float* __restrict__ in, u16* __restrict__ out, int n4)
{
    int i = blockIdx.x * 256 + threadIdx.x;
    if (i >= n4) return;
    float4 v = ((const float4*)in)[i];
    ushort4v o;
    o.x = f2bf(v.x); o.y = f2bf(v.y); o.z = f2bf(v.z); o.w = f2bf(v.w);
    ((ushort4v*)out)[i] = o;
}

// ---------------- depthwise weight norm: dwf[b][c][k] = d_w/||.||_k * d_g ---
__global__ __launch_bounds__(256)
void dnorm_k(const float* __restrict__ d_w, const float* __restrict__ d_g,
             float* __restrict__ dwf)
{
    __shared__ float red[KW][256];
    __shared__ float nrm[KW];
    const int b = blockIdx.x;
    const int tid = threadIdx.x;
    float s[KW];
#pragma unroll
    for (int k = 0; k < KW; k++) s[k] = 0.f;
    for (int c = tid; c < C_; c += 256) {
#pragma unroll
        for (int k = 0; k < KW; k++) {
            float v = d_w[((size_t)b * C_ + c) * KW + k];
            s[k] += v * v;
        }
    }
#pragma unroll
    for (int k = 0; k < KW; k++) red[k][tid] = s[k];
    __syncthreads();
    if (tid < KW) {
        float t = 0.f;
        for (int i = 0; i < 256; i++) t += red[tid][i];
        nrm[tid] = fmaxf(sqrtf(t), EPSF);
    }
    __syncthreads();
    for (int c = tid; c < C_; c += 256) {
        float g = d_g[(size_t)b * C_ + c];
#pragma unroll
        for (int k = 0; k < KW; k++)
            dwf[((size_t)b * C_ + c) * KW + k] =
                d_w[((size_t)b * C_ + c) * KW + k] / nrm[k] * g;
    }
}

// -------- transpose + gain + fused sum-of-squares partials -------------------
// pwT[b][o][c] = p_w[b][c][o] * p_g[b][c]   (inv_np applied in GEMM2 epilogue)
// part[b][cchunk][o] = sum_{c in chunk} p_w^2
__global__ __launch_bounds__(256)
void ptrans_k(const float* __restrict__ p_w, const float* __restrict__ p_g,
              float* __restrict__ part, u16* __restrict__ pwT)
{
    __shared__ float ts[64][65];
    __shared__ float sq[4][64];
    const int b  = blockIdx.z;
    const int c0 = blockIdx.y * 64, o0 = blockIdx.x * 64;
    const int tid = threadIdx.x;
    const int col = tid & 63;
    const int rg  = tid >> 6;
    float ssq = 0.f;
    for (int r = rg; r < 64; r += 4) {
        float v = p_w[((size_t)b * C_ + c0 + r) * O_ + o0 + col];
        ssq += v * v;
        ts[r][col] = v * p_g[(size_t)b * C_ + c0 + r];
    }
    sq[rg][col] = ssq;
    __syncthreads();
    if (tid < 64)
        part[((size_t)b * 16 + blockIdx.y) * O_ + o0 + tid] =
            sq[0][tid] + sq[1][tid] + sq[2][tid] + sq[3][tid];
    for (int r = rg; r < 64; r += 4)
        pwT[((size_t)b * O_ + o0 + r) * C_ + c0 + col] = f2bf(ts[col][r]);
}

// ------- finalize: inv_np[b][o] = 1/max(sqrt(sum_ch part),eps) ---------------
__global__ __launch_bounds__(256)
void pfin_k(const float* __restrict__ part, float* __restrict__ inv_np)
{
    const int b = blockIdx.y;
    const int o = blockIdx.x * 256 + threadIdx.x;
    float s = 0.f;
#pragma unroll
    for (int ch = 0; ch < 16; ch++)
        s += part[((size_t)b * 16 + ch) * O_ + o];
    inv_np[b * O_ + o] = 1.f / fmaxf(sqrtf(s), EPSF);
}

// ---------------- depthwise conv along t + transpose write -------------------
// h layout [C][B*T]; y1gT[bt][c] = sum_k h[c][bt+k-4]*dwf[b][c][k] + d_b[b][c]
__global__ __launch_bounds__(256)
void dwconv_k(const u16* __restrict__ h, const float* __restrict__ dwf,
              const float* __restrict__ d_b, u16* __restrict__ y1gT)
{
    __shared__ u16 hs[64][74];
    const int b  = blockIdx.z;
    const int c0 = blockIdx.y * 64, t0 = blockIdx.x * 64;
    const int tid = threadIdx.x;
    for (int idx = tid; idx < 64 * 72; idx += 256) {
        int cc = idx / 72, tt = idx % 72;
        int t = t0 + tt - 4;
        u16 v = 0;
        if (t >= 0 && t < T_) v = h[(size_t)(c0 + cc) * BT_ + b * T_ + t];
        hs[cc][tt] = v;
    }
    __syncthreads();
    const int cc = tid & 63;
    const int c  = c0 + cc;
    float w[KW];
#pragma unroll
    for (int k = 0; k < KW; k++) w[k] = dwf[((size_t)b * C_ + c) * KW + k];
    const float bb = d_b[(size_t)b * C_ + c];
    for (int tt = tid >> 6; tt < 64; tt += 4) {
        float s = bb;
#pragma unroll
        for (int k = 0; k < KW; k++) s += bf2f(hs[cc][tt + k]) * w[k];
        y1gT[((size_t)b * T_ + t0 + tt) * C_ + c] = f2bf(s);
    }
}

// ---------------- shared GEMM: D[M,N] = A[M,K] * Bt[N,K]^T, K-contig both ----
// BK=64, XOR-swizzled LDS, global_load_lds w16, double-buffered 2-phase
// prefetch (1 barrier/K-step), XCD-chunked block swizzle.
// EPI 0: D(bf16) = mish(v + bias[row])            (GEMM1: bias=w1_b)
// EPI 1: D(bf16) = v*inv[col] + bias[col]         (GEMM2: per-batch pwT/p_b)
// EPI 2: D(f32)  = v + bias[col] + X[row,col]     (GEMM3: bias=w2_b, X=resid)
template<int EPI, int TNF>
__global__ __launch_bounds__(256)
void gemm_nk(const u16* __restrict__ A, const u16* __restrict__ Bt,
             void* __restrict__ Dv, const float* __restrict__ bias,
             const float* __restrict__ extra,
             int M, int N, int Kd)
{
    __shared__ u16 As[2][128 * 64];
    __shared__ u16 Bs[2][TNF * 32 * 64];

    // T1: XCD-chunked bijective swizzle (all grids have nwg % 8 == 0)
    const int gx = gridDim.x;
    const unsigned nwg = (unsigned)gx * gridDim.y;
    unsigned lin = blockIdx.y * gx + blockIdx.x;
    lin = (lin & 7u) * (nwg >> 3) + (lin >> 3);
    const int m0 = (int)(lin / gx) * 128;
    const int n0 = (int)(lin % gx) * (TNF * 32);

    // batch index for per-batch operands (GEMM2): M rows are b*T_+t
    const int b = (EPI == 1) ? (m0 >> 10) : 0;
    if (EPI == 1) {
        Bt   += (size_t)b * O_ * C_;
        bias += (size_t)b * O_;
        extra+= (size_t)b * O_;   // inv_np
    }
    u16*   Db = (EPI == 2) ? nullptr : (u16*)Dv;
    float* Df = (EPI == 2) ? (float*)Dv : nullptr;
    const float* X = (EPI == 2) ? extra : nullptr;

    const int tid  = threadIdx.x;
    const int lane = tid & 63, wave = tid >> 6;
    const int wm = (wave & 1) * 64, wn = (wave >> 1) * (TNF * 16);
    const int lr = lane & 15;

    // staging: each instr covers 8 rows x 128B; source col pre-swizzled
    const int sbase = wave * 8;
    const int srowL = lane >> 3;
    const int scolE = ((lane & 7) ^ srowL) * 8;

    f32x4 acc[4][TNF];
#pragma unroll
    for (int i = 0; i < 4; i++)
#pragma unroll
        for (int j = 0; j < TNF; j++) acc[i][j] = (f32x4){0.f, 0.f, 0.f, 0.f};

    auto STAGE = [&](int buf, int k0) {
#pragma unroll
        for (int i = 0; i < 4; i++)
            GLOAD_LDS16(&A[(size_t)(m0 + i * 32 + sbase + srowL) * Kd + k0 + scolE],
                        &As[buf][(i * 32 + sbase) * 64]);
#pragma unroll
        for (int i = 0; i < TNF; i++)
            GLOAD_LDS16(&Bt[(size_t)(n0 + i * 32 + sbase + srowL) * Kd + k0 + scolE],
                        &Bs[buf][(i * 32 + sbase) * 64]);
    };

    const int NT = Kd >> 6;
    STAGE(0, 0);
    for (int kt = 0; kt < NT; kt++) {
        __syncthreads();                 // drains STAGE(kt) (vmcnt->0) after prev MFMA
        if (kt + 1 < NT) STAGE((kt + 1) & 1, (kt + 1) << 6);
        const u16* as = As[kt & 1];
        const u16* bs = Bs[kt & 1];
        bf16x8 av[2][4], bv[2][TNF];
#pragma unroll
        for (int kk = 0; kk < 2; kk++) {
            const int slot = (lane >> 4) + kk * 4;
            const int sw = (slot ^ (lr & 7)) << 3;
#pragma unroll
            for (int i = 0; i < 4; i++)
                av[kk][i] = *(const bf16x8*)&as[(wm + i * 16 + lr) * 64 + sw];
#pragma unroll
            for (int j = 0; j < TNF; j++)
                bv[kk][j] = *(const bf16x8*)&bs[(wn + j * 16 + lr) * 64 + sw];
        }
#pragma unroll
        for (int kk = 0; kk < 2; kk++)
#pragma unroll
            for (int i = 0; i < 4; i++)
#pragma unroll
                for (int j = 0; j < TNF; j++)
                    acc[i][j] = __builtin_amdgcn_mfma_f32_16x16x32_bf16(
                        av[kk][i], bv[kk][j], acc[i][j], 0, 0, 0);
    }

    const int r0 = (lane >> 4) * 4;
#pragma unroll
    for (int i = 0; i < 4; i++) {
#pragma unroll
        for (int j = 0; j < TNF; j++) {
            const int col = n0 + wn + j * 16 + lr;
            float iv = (EPI == 1) ? extra[col] : 0.f;
#pragma unroll
            for (int r = 0; r < 4; r++) {
                const int row = m0 + wm + i * 16 + r0 + r;
                float v = acc[i][j][r];
                if (EPI == 0) {
                    v += bias[row];
                    v = mishf(v);
                    Db[(size_t)row * N + col] = f2bf(v);
                } else if (EPI == 1) {
                    v = v * iv + bias[col];
                    Db[(size_t)row * N + col] = f2bf(v);
                } else {
                    v += bias[col] + X[(size_t)row * N + col];
                    Df[(size_t)row * N + col] = v;
                }
            }
        }
    }
}

extern "C" void kernel_launch(void* const* d_in, const int* in_sizes, int n_in,
                              void* d_out, int out_size, void* d_ws, size_t ws_size,
                              hipStream_t stream)
{
    const float* x   = (const float*)d_in[0];
    const float* d_w = (const float*)d_in[1];
    const float* d_g = (const float*)d_in[2];
    const float* d_b = (const float*)d_in[3];
    const float* p_w = (const float*)d_in[4];
    const float* p_g = (const float*)d_in[5];
    const float* p_b = (const float*)d_in[6];
    const float* w1w = (const float*)d_in[7];
    const float* w1b = (const float*)d_in[8];
    const float* w2w = (const float*)d_in[9];
    const float* w2b = (const float*)d_in[10];
    float* out = (float*)d_out;

    char* ws = (char*)d_ws;
    const size_t SZ = (size_t)16777216;           // 16 MB
    u16*   h    = (u16*)(ws);                     // [C][B*T] bf16
    u16*   y1gT = (u16*)(ws + SZ);                // [B*T][C] bf16
    u16*   pwT  = (u16*)(ws + 2 * SZ);            // [B][O][C] bf16
    u16*   y2T  = (u16*)(ws + 3 * SZ);            // [B*T][O] bf16
    u16*   xb   = (u16*)(ws + 4 * SZ);            // [B*T][DI] bf16 (4 MB)
    u16*   w1b16= (u16*)(ws + 4 * SZ + 4194304);  // [C][DI] bf16
    u16*   w2b16= (u16*)(ws + 4 * SZ + 4718592);  // [DI][O] bf16
    float* dwf  = (float*)(ws + 4 * SZ + 5242880);           // B*C*KW f32
    float* inv  = (float*)(ws + 4 * SZ + 5242880 + 294912);  // B*O f32
    float* part = (float*)(ws + 4 * SZ + 5242880 + 327680);  // B*16*O f32

    cvt_k<<<dim3((BT_ * DI_) / 4 / 256), 256, 0, stream>>>(x,   xb,    (BT_ * DI_) / 4);
    cvt_k<<<dim3((C_ * DI_) / 4 / 256), 256, 0, stream>>>(w1w, w1b16, (C_ * DI_) / 4);
    cvt_k<<<dim3((DI_ * O_) / 4 / 256), 256, 0, stream>>>(w2w, w2b16, (DI_ * O_) / 4);

    dnorm_k<<<dim3(B_), 256, 0, stream>>>(d_w, d_g, dwf);
    ptrans_k<<<dim3(O_ / 64, C_ / 64, B_), 256, 0, stream>>>(p_w, p_g, part, pwT);
    pfin_k<<<dim3(O_ / 256, B_), 256, 0, stream>>>(part, inv);

    // GEMM1: h[c][bt] = mish(w1[c,:] . xb[bt,:] + w1b[c]);  M=C, N=B*T, K=DI
    gemm_nk<0, 4><<<dim3(BT_ / 128, C_ / 128), 256, 0, stream>>>(
        w1b16, xb, h, w1b, nullptr, C_, BT_, DI_);

    dwconv_k<<<dim3(T_ / 64, C_ / 64, B_), 256, 0, stream>>>(h, dwf, d_b, y1gT);

    // GEMM2: y2T[bt][o] = (y1gT[bt,:] . pwT[b][o,:])*inv[b][o] + p_b[b][o]
    gemm_nk<1, 4><<<dim3(O_ / 128, BT_ / 128), 256, 0, stream>>>(
        y1gT, pwT, y2T, p_b, inv, BT_, O_, C_);

    // GEMM3: out[bt][i] = y2T[bt,:] . w2[i,:] + w2b[i] + x[bt][i];  N=DI, 64-wide
    gemm_nk<2, 2><<<dim3(DI_ / 64, BT_ / 128), 256, 0, stream>>>(
        y2T, w2b16, out, w2b, x, BT_, DI_, O_);
}

// Round 6
// 102.549 us; speedup vs baseline: 1.7008x; 1.0748x over previous
//
#include <hip/hip_runtime.h>
#include <hip/hip_bf16.h>

#define B_  8
#define T_  1024
#define DI_ 256
#define C_  1024
#define O_  1024
#define KW  9
#define BT_ 8192
#define EPSF 1e-12f

typedef unsigned short u16;
typedef u16   ushort8 __attribute__((ext_vector_type(8)));
typedef u16   ushort4v __attribute__((ext_vector_type(4)));
typedef __bf16 bf16x8 __attribute__((ext_vector_type(8)));
typedef float  f32x4  __attribute__((ext_vector_type(4)));

#define GLOAD_LDS16(g, l) __builtin_amdgcn_global_load_lds( \
    (const __attribute__((address_space(1))) void*)(g),      \
    (__attribute__((address_space(3))) void*)(l), 16, 0, 0)

__device__ __forceinline__ float bf2f(u16 u) {
    union { unsigned int i; float f; } z; z.i = ((unsigned int)u) << 16; return z.f;
}
__device__ __forceinline__ u16 f2bf(float f) {
    union { float f; unsigned int i; } z; z.f = f;
    unsigned int i = z.i;
    i += 0x7FFFu + ((i >> 16) & 1u);   // RNE
    return (u16)(i >> 16);
}
__device__ __forceinline__ float mishf(float v) {
    float u = __expf(v);
    float w = 1.f + u;
    return v * (1.f - 2.f / (w * w + 1.f));
}

// ================= mega prep kernel =========================================
// block ranges: [0,2048) cvt xb | [2048,2304) cvt w1 | [2304,2560) cvt w2
//             | [2560,2568) dnorm | [2568,4616) ptrans(+ssq partials)
#define PB_XB 2048
#define PB_W1 2304
#define PB_W2 2560
#define PB_DN 2568
#define PB_PT 4616

__global__ __launch_bounds__(256)
void prep_k(const float* __restrict__ x,   u16* __restrict__ xb,
            const float* __restrict__ w1w, u16* __restrict__ w1b16,
            const float* __restrict__ w2w, u16* __restrict__ w2b16,
            const float* __restrict__ d_w, const float* __restrict__ d_g,
            float* __restrict__ dwf,
            const float* __restrict__ p_w, const float* __restrict__ p_g,
            float* __restrict__ part, u16* __restrict__ pwT)
{
    const int bid = blockIdx.x;
    const int tid = threadIdx.x;

    if (bid < PB_W2) {
        // ---- f32 -> bf16 converts ----
        const float* in;
        u16* out;
        int i;
        if (bid < PB_XB)      { in = x;   out = xb;    i = bid * 256 + tid; }
        else if (bid < PB_W1) { in = w1w; out = w1b16; i = (bid - PB_XB) * 256 + tid; }
        else                  { in = w2w; out = w2b16; i = (bid - PB_W1) * 256 + tid; }
        float4 v = ((const float4*)in)[i];
        ushort4v o;
        o.x = f2bf(v.x); o.y = f2bf(v.y); o.z = f2bf(v.z); o.w = f2bf(v.w);
        ((ushort4v*)out)[i] = o;
    } else if (bid < PB_DN) {
        // ---- depthwise weight norm: dwf[b][c][k] = d_w/||.||_k * d_g ----
        __shared__ float red[KW][256];
        __shared__ float nrm[KW];
        const int b = bid - PB_W2;
        float s[KW];
#pragma unroll
        for (int k = 0; k < KW; k++) s[k] = 0.f;
        for (int c = tid; c < C_; c += 256) {
#pragma unroll
            for (int k = 0; k < KW; k++) {
                float v = d_w[((size_t)b * C_ + c) * KW + k];
                s[k] += v * v;
            }
        }
#pragma unroll
        for (int k = 0; k < KW; k++) red[k][tid] = s[k];
        __syncthreads();
        if (tid < KW) {
            float t = 0.f;
            for (int i = 0; i < 256; i++) t += red[tid][i];
            nrm[tid] = fmaxf(sqrtf(t), EPSF);
        }
        __syncthreads();
        for (int c = tid; c < C_; c += 256) {
            float g = d_g[(size_t)b * C_ + c];
#pragma unroll
            for (int k = 0; k < KW; k++)
                dwf[((size_t)b * C_ + c) * KW + k] =
                    d_w[((size_t)b * C_ + c) * KW + k] / nrm[k] * g;
        }
    } else {
        // ---- transpose + gain + ssq partials ----
        // pwT[b][o][c] = p_w[b][c][o]*p_g[b][c]; part[b][cch][o] = sum p_w^2
        __shared__ float ts[64][65];
        __shared__ float sq[4][64];
        const int idx = bid - PB_DN;
        const int b   = idx >> 8;
        const int rem = idx & 255;
        const int c0  = (rem >> 4) * 64, o0 = (rem & 15) * 64;
        const int col = tid & 63;
        const int rg  = tid >> 6;
        float ssq = 0.f;
        for (int r = rg; r < 64; r += 4) {
            float v = p_w[((size_t)b * C_ + c0 + r) * O_ + o0 + col];
            ssq += v * v;
            ts[r][col] = v * p_g[(size_t)b * C_ + c0 + r];
        }
        sq[rg][col] = ssq;
        __syncthreads();
        if (tid < 64)
            part[((size_t)b * 16 + (rem >> 4)) * O_ + o0 + tid] =
                sq[0][tid] + sq[1][tid] + sq[2][tid] + sq[3][tid];
        for (int r = rg; r < 64; r += 4)
            pwT[((size_t)b * O_ + o0 + r) * C_ + c0 + col] = f2bf(ts[col][r]);
    }
}

// ---------------- depthwise conv along t + transpose write -------------------
// h layout [C][B*T]; y1gT[bt][c] = sum_k h[c][bt+k-4]*dwf[b][c][k] + d_b[b][c]
__global__ __launch_bounds__(256)
void dwconv_k(const u16* __restrict__ h, const float* __restrict__ dwf,
              const float* __restrict__ d_b, u16* __restrict__ y1gT)
{
    __shared__ u16 hs[64][74];
    const int b  = blockIdx.z;
    const int c0 = blockIdx.y * 64, t0 = blockIdx.x * 64;
    const int tid = threadIdx.x;
    for (int idx = tid; idx < 64 * 72; idx += 256) {
        int cc = idx / 72, tt = idx % 72;
        int t = t0 + tt - 4;
        u16 v = 0;
        if (t >= 0 && t < T_) v = h[(size_t)(c0 + cc) * BT_ + b * T_ + t];
        hs[cc][tt] = v;
    }
    __syncthreads();
    const int cc = tid & 63;
    const int c  = c0 + cc;
    float w[KW];
#pragma unroll
    for (int k = 0; k < KW; k++) w[k] = dwf[((size_t)b * C_ + c) * KW + k];
    const float bb = d_b[(size_t)b * C_ + c];
    for (int tt = tid >> 6; tt < 64; tt += 4) {
        float s = bb;
#pragma unroll
        for (int k = 0; k < KW; k++) s += bf2f(hs[cc][tt + k]) * w[k];
        y1gT[((size_t)b * T_ + t0 + tt) * C_ + c] = f2bf(s);
    }
}

// ---------------- shared GEMM: D[M,N] = A[M,K] * Bt[N,K]^T, K-contig both ----
// BK=64, XOR-swizzled LDS, global_load_lds w16, double-buffered 2-phase
// prefetch (1 barrier/K-step), XCD-chunked block swizzle.
// EPI 0: D(bf16) = mish(v + bias[row])               (GEMM1: bias=w1_b)
// EPI 1: D(bf16) = v*inv(part,col) + bias[col]       (GEMM2: extra=part)
// EPI 2: D(f32)  = v + bias[col] + X[row,col]        (GEMM3: extra=resid)
template<int EPI, int TNF>
__global__ __launch_bounds__(256)
void gemm_nk(const u16* __restrict__ A, const u16* __restrict__ Bt,
             void* __restrict__ Dv, const float* __restrict__ bias,
             const float* __restrict__ extra,
             int M, int N, int Kd)
{
    __shared__ u16 As[2][128 * 64];
    __shared__ u16 Bs[2][TNF * 32 * 64];

    // T1: XCD-chunked bijective swizzle (all grids have nwg % 8 == 0)
    const int gx = gridDim.x;
    const unsigned nwg = (unsigned)gx * gridDim.y;
    unsigned lin = blockIdx.y * gx + blockIdx.x;
    lin = (lin & 7u) * (nwg >> 3) + (lin >> 3);
    const int m0 = (int)(lin / gx) * 128;
    const int n0 = (int)(lin % gx) * (TNF * 32);

    // batch index for per-batch operands (GEMM2): M rows are b*T_+t
    const int b = (EPI == 1) ? (m0 >> 10) : 0;
    if (EPI == 1) {
        Bt   += (size_t)b * O_ * C_;
        bias += (size_t)b * O_;
        extra+= (size_t)b * 16 * O_;   // ssq partials
    }
    u16*   Db = (EPI == 2) ? nullptr : (u16*)Dv;
    float* Df = (EPI == 2) ? (float*)Dv : nullptr;
    const float* X = (EPI == 2) ? extra : nullptr;

    const int tid  = threadIdx.x;
    const int lane = tid & 63, wave = tid >> 6;
    const int wm = (wave & 1) * 64, wn = (wave >> 1) * (TNF * 16);
    const int lr = lane & 15;

    // staging: each instr covers 8 rows x 128B; source col pre-swizzled
    const int sbase = wave * 8;
    const int srowL = lane >> 3;
    const int scolE = ((lane & 7) ^ srowL) * 8;

    f32x4 acc[4][TNF];
#pragma unroll
    for (int i = 0; i < 4; i++)
#pragma unroll
        for (int j = 0; j < TNF; j++) acc[i][j] = (f32x4){0.f, 0.f, 0.f, 0.f};

    auto STAGE = [&](int buf, int k0) {
#pragma unroll
        for (int i = 0; i < 4; i++)
            GLOAD_LDS16(&A[(size_t)(m0 + i * 32 + sbase + srowL) * Kd + k0 + scolE],
                        &As[buf][(i * 32 + sbase) * 64]);
#pragma unroll
        for (int i = 0; i < TNF; i++)
            GLOAD_LDS16(&Bt[(size_t)(n0 + i * 32 + sbase + srowL) * Kd + k0 + scolE],
                        &Bs[buf][(i * 32 + sbase) * 64]);
    };

    const int NT = Kd >> 6;
    STAGE(0, 0);
    for (int kt = 0; kt < NT; kt++) {
        __syncthreads();                 // drains STAGE(kt) after prev MFMA phase
        if (kt + 1 < NT) STAGE((kt + 1) & 1, (kt + 1) << 6);
        const u16* as = As[kt & 1];
        const u16* bs = Bs[kt & 1];
        bf16x8 av[2][4], bv[2][TNF];
#pragma unroll
        for (int kk = 0; kk < 2; kk++) {
            const int slot = (lane >> 4) + kk * 4;
            const int sw = (slot ^ (lr & 7)) << 3;
#pragma unroll
            for (int i = 0; i < 4; i++)
                av[kk][i] = *(const bf16x8*)&as[(wm + i * 16 + lr) * 64 + sw];
#pragma unroll
            for (int j = 0; j < TNF; j++)
                bv[kk][j] = *(const bf16x8*)&bs[(wn + j * 16 + lr) * 64 + sw];
        }
#pragma unroll
        for (int kk = 0; kk < 2; kk++)
#pragma unroll
            for (int i = 0; i < 4; i++)
#pragma unroll
                for (int j = 0; j < TNF; j++)
                    acc[i][j] = __builtin_amdgcn_mfma_f32_16x16x32_bf16(
                        av[kk][i], bv[kk][j], acc[i][j], 0, 0, 0);
    }

    const int r0 = (lane >> 4) * 4;
#pragma unroll
    for (int i = 0; i < 4; i++) {
#pragma unroll
        for (int j = 0; j < TNF; j++) {
            const int col = n0 + wn + j * 16 + lr;
            float iv = 0.f;
            if (EPI == 1) {
                float s = 0.f;
#pragma unroll
                for (int ch = 0; ch < 16; ch++)
                    s += extra[(size_t)ch * O_ + col];
                iv = 1.f / fmaxf(sqrtf(s), EPSF);
            }
#pragma unroll
            for (int r = 0; r < 4; r++) {
                const int row = m0 + wm + i * 16 + r0 + r;
                float v = acc[i][j][r];
                if (EPI == 0) {
                    v += bias[row];
                    v = mishf(v);
                    Db[(size_t)row * N + col] = f2bf(v);
                } else if (EPI == 1) {
                    v = v * iv + bias[col];
                    Db[(size_t)row * N + col] = f2bf(v);
                } else {
                    v += bias[col] + X[(size_t)row * N + col];
                    Df[(size_t)row * N + col] = v;
                }
            }
        }
    }
}

extern "C" void kernel_launch(void* const* d_in, const int* in_sizes, int n_in,
                              void* d_out, int out_size, void* d_ws, size_t ws_size,
                              hipStream_t stream)
{
    const float* x   = (const float*)d_in[0];
    const float* d_w = (const float*)d_in[1];
    const float* d_g = (const float*)d_in[2];
    const float* d_b = (const float*)d_in[3];
    const float* p_w = (const float*)d_in[4];
    const float* p_g = (const float*)d_in[5];
    const float* p_b = (const float*)d_in[6];
    const float* w1w = (const float*)d_in[7];
    const float* w1b = (const float*)d_in[8];
    const float* w2w = (const float*)d_in[9];
    const float* w2b = (const float*)d_in[10];
    float* out = (float*)d_out;

    char* ws = (char*)d_ws;
    const size_t SZ = (size_t)16777216;           // 16 MB
    u16*   h    = (u16*)(ws);                     // [C][B*T] bf16
    u16*   y1gT = (u16*)(ws + SZ);                // [B*T][C] bf16
    u16*   pwT  = (u16*)(ws + 2 * SZ);            // [B][O][C] bf16
    u16*   y2T  = (u16*)(ws + 3 * SZ);            // [B*T][O] bf16
    u16*   xb   = (u16*)(ws + 4 * SZ);            // [B*T][DI] bf16 (4 MB)
    u16*   w1b16= (u16*)(ws + 4 * SZ + 4194304);  // [C][DI] bf16
    u16*   w2b16= (u16*)(ws + 4 * SZ + 4718592);  // [DI][O] bf16
    float* dwf  = (float*)(ws + 4 * SZ + 5242880);           // B*C*KW f32
    float* part = (float*)(ws + 4 * SZ + 5242880 + 294912);  // B*16*O f32

    prep_k<<<dim3(PB_PT), 256, 0, stream>>>(
        x, xb, w1w, w1b16, w2w, w2b16, d_w, d_g, dwf, p_w, p_g, part, pwT);

    // GEMM1: h[c][bt] = mish(w1[c,:] . xb[bt,:] + w1b[c]);  M=C, N=B*T, K=DI
    gemm_nk<0, 4><<<dim3(BT_ / 128, C_ / 128), 256, 0, stream>>>(
        w1b16, xb, h, w1b, nullptr, C_, BT_, DI_);

    dwconv_k<<<dim3(T_ / 64, C_ / 64, B_), 256, 0, stream>>>(h, dwf, d_b, y1gT);

    // GEMM2: y2T[bt][o] = (y1gT[bt,:] . pwT[b][o,:])*inv[b][o] + p_b[b][o]
    gemm_nk<1, 4><<<dim3(O_ / 128, BT_ / 128), 256, 0, stream>>>(
        y1gT, pwT, y2T, p_b, part, BT_, O_, C_);

    // GEMM3: out[bt][i] = y2T[bt,:] . w2[i,:] + w2b[i] + x[bt][i];  N=DI, 64-wide
    gemm_nk<2, 2><<<dim3(DI_ / 64, BT_ / 128), 256, 0, stream>>>(
        y2T, w2b16, out, w2b, x, BT_, DI_, O_);
}